// Round 1
// baseline (1515.809 us; speedup 1.0000x reference)
//
#include <hip/hip_runtime.h>

#define N 8192
#define NF4 (N / 4)  // 2048 float4 per row

__device__ __forceinline__ float4 fabs4(float4 v) {
    v.x = fabsf(v.x); v.y = fabsf(v.y); v.z = fabsf(v.z); v.w = fabsf(v.w);
    return v;
}

// b0 = 1.0 (C starts as all-ones; C is represented as 1/b)
__global__ __launch_bounds__(256) void init_ones(float* __restrict__ b0) {
    b0[blockIdx.x * 256 + threadIdx.x] = 1.0f;
}

// Pass A (row matvec): R_i = 1 / sum_j |W_ij| * (1/b_prev_j).  Also zeros b_next.
// grid 512 blocks x 256 threads; 16 rows/block; each wave owns 4 rows.
__global__ __launch_bounds__(256) void pass_rows(const float* __restrict__ W,
                                                 const float* __restrict__ b_prev,
                                                 float* __restrict__ R,
                                                 float* __restrict__ b_next) {
    __shared__ float crcp[N];  // 32 KB: C_j = 1/b_prev_j
    const int tid = threadIdx.x;

    // stage reciprocals of b_prev into LDS (b_prev is L2-hot, ~0 HBM cost)
#pragma unroll
    for (int k = 0; k < 8; k++) {
        int f = k * 256 + tid;
        float4 b = ((const float4*)b_prev)[f];
        float4 c;
        c.x = 1.0f / b.x; c.y = 1.0f / b.y; c.z = 1.0f / b.z; c.w = 1.0f / b.w;
        ((float4*)crcp)[f] = c;
    }
    // zero a disjoint 16-element slice of b_next (8192 / 512 blocks = 16)
    if (tid < 16) b_next[blockIdx.x * 16 + tid] = 0.0f;
    __syncthreads();

    const int wave = tid >> 6, lane = tid & 63;
    const int row0 = blockIdx.x * 16 + wave * 4;

    for (int rr = 0; rr < 4; rr++) {
        const int row = row0 + rr;
        const float4* wr = (const float4*)(W + (size_t)row * N);
        float4 a0 = {0, 0, 0, 0}, a1 = {0, 0, 0, 0};
#pragma unroll
        for (int k = 0; k < 32; k += 2) {
            int f0 = k * 64 + lane;
            int f1 = f0 + 64;
            float4 w0 = fabs4(wr[f0]);
            float4 w1 = fabs4(wr[f1]);
            float4 c0 = ((const float4*)crcp)[f0];
            float4 c1 = ((const float4*)crcp)[f1];
            a0.x = fmaf(w0.x, c0.x, a0.x); a0.y = fmaf(w0.y, c0.y, a0.y);
            a0.z = fmaf(w0.z, c0.z, a0.z); a0.w = fmaf(w0.w, c0.w, a0.w);
            a1.x = fmaf(w1.x, c1.x, a1.x); a1.y = fmaf(w1.y, c1.y, a1.y);
            a1.z = fmaf(w1.z, c1.z, a1.z); a1.w = fmaf(w1.w, c1.w, a1.w);
        }
        float s = ((a0.x + a1.x) + (a0.y + a1.y)) + ((a0.z + a1.z) + (a0.w + a1.w));
        // wave-level tree reduction over 64 lanes
        for (int off = 32; off > 0; off >>= 1) s += __shfl_down(s, off);
        if (lane == 0) R[row] = 1.0f / s;
    }
}

// Pass B (col matvec): b_next_j += sum_i |W_ij| * R_i, split-K with atomics.
// grid = 8 column-tiles (1024 cols each) x 64 row-chunks (128 rows each) = 512 blocks.
__global__ __launch_bounds__(256) void pass_cols(const float* __restrict__ W,
                                                 const float* __restrict__ R,
                                                 float* __restrict__ b_next) {
    __shared__ float rloc[128];
    const int tid = threadIdx.x;
    const int ctile = blockIdx.x & 7;
    const int chunk = blockIdx.x >> 3;
    const int row0 = chunk * 128;

    if (tid < 128) rloc[tid] = R[row0 + tid];
    __syncthreads();

    const int f = ctile * 256 + tid;  // float4 column index, 0..2047
    const float4* Wf = (const float4*)W;
    float4 acc = {0, 0, 0, 0};
#pragma unroll 4
    for (int i = 0; i < 128; i++) {
        float4 w = fabs4(Wf[(size_t)(row0 + i) * NF4 + f]);
        float r = rloc[i];  // broadcast read, conflict-free
        acc.x = fmaf(w.x, r, acc.x); acc.y = fmaf(w.y, r, acc.y);
        acc.z = fmaf(w.z, r, acc.z); acc.w = fmaf(w.w, r, acc.w);
    }
    float* dst = b_next + f * 4;
    atomicAdd(dst + 0, acc.x);
    atomicAdd(dst + 1, acc.y);
    atomicAdd(dst + 2, acc.z);
    atomicAdd(dst + 3, acc.w);
}

// Final: out_ij = R_i * |W_ij| * (1/b_last_j)
// grid 1024 blocks x 256 threads; 8 rows/block; each wave owns 2 rows.
__global__ __launch_bounds__(256) void finalize(const float* __restrict__ W,
                                                const float* __restrict__ R,
                                                const float* __restrict__ b_last,
                                                float* __restrict__ out) {
    __shared__ float crcp[N];
    const int tid = threadIdx.x;
#pragma unroll
    for (int k = 0; k < 8; k++) {
        int f = k * 256 + tid;
        float4 b = ((const float4*)b_last)[f];
        float4 c;
        c.x = 1.0f / b.x; c.y = 1.0f / b.y; c.z = 1.0f / b.z; c.w = 1.0f / b.w;
        ((float4*)crcp)[f] = c;
    }
    __syncthreads();

    const int wave = tid >> 6, lane = tid & 63;
    const int row0 = blockIdx.x * 8 + wave * 2;
    for (int rr = 0; rr < 2; rr++) {
        const int row = row0 + rr;
        const float r = R[row];
        const float4* wr = (const float4*)(W + (size_t)row * N);
        float4* orow = (float4*)(out + (size_t)row * N);
#pragma unroll 4
        for (int k = 0; k < 32; k++) {
            int f = k * 64 + lane;
            float4 w = fabs4(wr[f]);
            float4 c = ((const float4*)crcp)[f];
            float4 o;
            o.x = r * w.x * c.x; o.y = r * w.y * c.y;
            o.z = r * w.z * c.z; o.w = r * w.w * c.w;
            orow[f] = o;
        }
    }
}

extern "C" void kernel_launch(void* const* d_in, const int* in_sizes, int n_in,
                              void* d_out, int out_size, void* d_ws, size_t ws_size,
                              hipStream_t stream) {
    const float* W = (const float*)d_in[0];
    float* out = (float*)d_out;

    // workspace layout: R | b0 | b1  (3 x 8192 floats = 96 KB)
    float* R  = (float*)d_ws;
    float* b0 = R + N;
    float* b1 = b0 + N;
    float* bufs[2] = {b0, b1};

    init_ones<<<N / 256, 256, 0, stream>>>(b0);

    for (int k = 1; k <= 10; k++) {
        float* prev = bufs[(k - 1) & 1];
        float* next = bufs[k & 1];
        pass_rows<<<512, 256, 0, stream>>>(W, prev, R, next);
        pass_cols<<<512, 256, 0, stream>>>(W, R, next);
    }
    // after iter 10: next == b0 holds the last column sums; R holds last row scales
    finalize<<<1024, 256, 0, stream>>>(W, R, b0, out);
}

// Round 2
// 957.062 us; speedup vs baseline: 1.5838x; 1.5838x over previous
//
#include <hip/hip_runtime.h>

#define N 8192

// ---- bf16 helpers (manual, branch-free RNE) ----
__device__ __forceinline__ unsigned int f2bf_rne(float f) {
    unsigned int u = __float_as_uint(f);
    u += 0x7fffu + ((u >> 16) & 1u);
    return u >> 16;
}
__device__ __forceinline__ unsigned int pack2(float a, float b) {
    return f2bf_rne(a) | (f2bf_rne(b) << 16);
}
__device__ __forceinline__ float bf_lo(unsigned int u) { return __uint_as_float(u << 16); }
__device__ __forceinline__ float bf_hi(unsigned int u) { return __uint_as_float(u & 0xffff0000u); }

// prep: A = bf16(|W|) (row-major), R_i = 1/rowsum(A_i) (iter-1 row pass), zero b0.
// 2048 blocks x 256; one row per wave.
__global__ __launch_bounds__(256) void prep(const float* __restrict__ W,
                                            unsigned int* __restrict__ A,  // 2 bf16 per uint
                                            float* __restrict__ R,
                                            float* __restrict__ b0) {
    const int tid = threadIdx.x;
    if (blockIdx.x < 32) b0[blockIdx.x * 256 + tid] = 0.0f;

    const int wave = tid >> 6, lane = tid & 63;
    const int row = blockIdx.x * 4 + wave;
    const float4* wr = (const float4*)(W + (size_t)row * N);
    uint4* ar = (uint4*)(A + (size_t)row * (N / 2));  // uint4 = 8 bf16 cols
    float s = 0.0f;
#pragma unroll 4
    for (int it = 0; it < 16; it++) {
        int g = it * 64 + lane;  // 8-col group
        float4 w0 = wr[2 * g];
        float4 w1 = wr[2 * g + 1];
        uint4 p;
        p.x = pack2(fabsf(w0.x), fabsf(w0.y));
        p.y = pack2(fabsf(w0.z), fabsf(w0.w));
        p.z = pack2(fabsf(w1.x), fabsf(w1.y));
        p.w = pack2(fabsf(w1.z), fabsf(w1.w));
        ar[g] = p;
        // sum the *quantized* values so later passes are self-consistent
        s += ((bf_lo(p.x) + bf_hi(p.x)) + (bf_lo(p.y) + bf_hi(p.y))) +
             ((bf_lo(p.z) + bf_hi(p.z)) + (bf_lo(p.w) + bf_hi(p.w)));
    }
    for (int off = 32; off > 0; off >>= 1) s += __shfl_down(s, off);
    if (lane == 0) R[row] = 1.0f / s;
}

// pass_rows: R_i = 1 / sum_j A_ij * (1/b_prev_j); zeros b_next.
// 1024 blocks x 256; 8 rows/block, 2 rows per wave.
__global__ __launch_bounds__(256) void pass_rows(const unsigned short* __restrict__ A,
                                                 const float* __restrict__ b_prev,
                                                 float* __restrict__ R,
                                                 float* __restrict__ b_next) {
    __shared__ float crcp[N];  // 32 KB
    const int tid = threadIdx.x;
#pragma unroll
    for (int k = 0; k < 8; k++) {
        int f = k * 256 + tid;
        float4 b = ((const float4*)b_prev)[f];
        float4 c;
        c.x = 1.0f / b.x; c.y = 1.0f / b.y; c.z = 1.0f / b.z; c.w = 1.0f / b.w;
        ((float4*)crcp)[f] = c;
    }
    if (tid < 8) b_next[blockIdx.x * 8 + tid] = 0.0f;
    __syncthreads();

    const int wave = tid >> 6, lane = tid & 63;
    for (int rr = 0; rr < 2; rr++) {
        const int row = blockIdx.x * 8 + wave * 2 + rr;
        const uint2* ar = (const uint2*)(A + (size_t)row * N);  // uint2 = 4 bf16 cols
        float4 a0 = {0, 0, 0, 0}, a1 = {0, 0, 0, 0};
#pragma unroll 8
        for (int k = 0; k < 32; k += 2) {
            int f0 = k * 64 + lane;   // float4-col group 0..2047
            int f1 = f0 + 64;
            uint2 u0 = ar[f0];
            uint2 u1 = ar[f1];
            float4 c0 = ((const float4*)crcp)[f0];
            float4 c1 = ((const float4*)crcp)[f1];
            a0.x = fmaf(bf_lo(u0.x), c0.x, a0.x);
            a0.y = fmaf(bf_hi(u0.x), c0.y, a0.y);
            a0.z = fmaf(bf_lo(u0.y), c0.z, a0.z);
            a0.w = fmaf(bf_hi(u0.y), c0.w, a0.w);
            a1.x = fmaf(bf_lo(u1.x), c1.x, a1.x);
            a1.y = fmaf(bf_hi(u1.x), c1.y, a1.y);
            a1.z = fmaf(bf_lo(u1.y), c1.z, a1.z);
            a1.w = fmaf(bf_hi(u1.y), c1.w, a1.w);
        }
        float s = ((a0.x + a1.x) + (a0.y + a1.y)) + ((a0.z + a1.z) + (a0.w + a1.w));
        for (int off = 32; off > 0; off >>= 1) s += __shfl_down(s, off);
        if (lane == 0) R[row] = 1.0f / s;
    }
}

// pass_cols: b_next_j += sum_i A_ij * R_i, split-K atomics.
// 512 blocks = 8 col-tiles (1024 cols) x 64 row-chunks (128 rows).
__global__ __launch_bounds__(256) void pass_cols(const unsigned short* __restrict__ A,
                                                 const float* __restrict__ R,
                                                 float* __restrict__ b_next) {
    __shared__ float rloc[128];
    const int tid = threadIdx.x;
    const int ctile = blockIdx.x & 7;
    const int chunk = blockIdx.x >> 3;
    const int row0 = chunk * 128;

    if (tid < 128) rloc[tid] = R[row0 + tid];
    __syncthreads();

    const int f = ctile * 256 + tid;  // float4-col group 0..2047
    const uint2* Af = (const uint2*)A;
    float4 acc = {0, 0, 0, 0};
#pragma unroll 4
    for (int i = 0; i < 128; i++) {
        uint2 u = Af[(size_t)(row0 + i) * (N / 4) + f];
        float r = rloc[i];
        acc.x = fmaf(bf_lo(u.x), r, acc.x);
        acc.y = fmaf(bf_hi(u.x), r, acc.y);
        acc.z = fmaf(bf_lo(u.y), r, acc.z);
        acc.w = fmaf(bf_hi(u.y), r, acc.w);
    }
    float* dst = b_next + f * 4;
    atomicAdd(dst + 0, acc.x);
    atomicAdd(dst + 1, acc.y);
    atomicAdd(dst + 2, acc.z);
    atomicAdd(dst + 3, acc.w);
}

// finalize: out_ij = R_i * |W_ij| * (1/b_last_j). Exact fp32 W.
// 1024 blocks x 256; 8 rows/block, 2 per wave.
__global__ __launch_bounds__(256) void finalize(const float* __restrict__ W,
                                                const float* __restrict__ R,
                                                const float* __restrict__ b_last,
                                                float* __restrict__ out) {
    __shared__ float crcp[N];
    const int tid = threadIdx.x;
#pragma unroll
    for (int k = 0; k < 8; k++) {
        int f = k * 256 + tid;
        float4 b = ((const float4*)b_last)[f];
        float4 c;
        c.x = 1.0f / b.x; c.y = 1.0f / b.y; c.z = 1.0f / b.z; c.w = 1.0f / b.w;
        ((float4*)crcp)[f] = c;
    }
    __syncthreads();

    const int wave = tid >> 6, lane = tid & 63;
    const int row0 = blockIdx.x * 8 + wave * 2;
    for (int rr = 0; rr < 2; rr++) {
        const int row = row0 + rr;
        const float r = R[row];
        const float4* wr = (const float4*)(W + (size_t)row * N);
        float4* orow = (float4*)(out + (size_t)row * N);
#pragma unroll 4
        for (int k = 0; k < 32; k++) {
            int f = k * 64 + lane;
            float4 w = wr[f];
            float4 c = ((const float4*)crcp)[f];
            float4 o;
            o.x = r * fabsf(w.x) * c.x;
            o.y = r * fabsf(w.y) * c.y;
            o.z = r * fabsf(w.z) * c.z;
            o.w = r * fabsf(w.w) * c.w;
            orow[f] = o;
        }
    }
}

extern "C" void kernel_launch(void* const* d_in, const int* in_sizes, int n_in,
                              void* d_out, int out_size, void* d_ws, size_t ws_size,
                              hipStream_t stream) {
    const float* W = (const float*)d_in[0];
    float* out = (float*)d_out;

    // bf16 |W| scratch lives in the FIRST HALF of d_out (134 MB of 268 MB).
    // It is only needed during the matvec passes; finalize overwrites all of out.
    unsigned short* A = (unsigned short*)d_out;

    // vectors in d_ws: R | b0 | b1 (96 KB)
    float* R  = (float*)d_ws;
    float* b0 = R + N;
    float* b1 = b0 + N;

    // iter 1: prep fuses row pass (C=1) + bf16 conversion + zeroing b0
    prep<<<2048, 256, 0, stream>>>(W, (unsigned int*)A, R, b0);
    pass_cols<<<512, 256, 0, stream>>>(A, R, b0);

    float* bprev = b0;
    float* bnext = b1;
    for (int k = 2; k <= 10; k++) {
        pass_rows<<<1024, 256, 0, stream>>>(A, bprev, R, bnext);
        pass_cols<<<512, 256, 0, stream>>>(A, R, bnext);
        float* t = bprev; bprev = bnext; bnext = t;
    }
    // bprev holds the final column sums; R the final row scales
    finalize<<<1024, 256, 0, stream>>>(W, R, bprev, out);
}